// Round 7
// baseline (337.085 us; speedup 1.0000x reference)
//
#include <hip/hip_runtime.h>
#include <hip/hip_bf16.h>

// MultiAgentGRULoop round 7: software-pipelined cell (x-GEMM one step ahead).
//   - 256 blocks x 512 thr (8 waves), 1 block/CU, launch_bounds(512,1).
//   - Cell t: h-MFMA(t) -> [epilogue(t) with gI(t) from regs  ||  x-MFMA(t+1)
//     into fresh gI regs] -> lgkmcnt-only barrier. Epilogue trans/VALU chain
//     overlaps MFMA issue; per-cell x prefetch/convert/ds_write removed.
//   - x staged in 8-step LDS chunks (dbuf, 70 KB): loads issued at chunk
//     iter 0, converted+written at iter 2 (fully unrolled -> static offsets).
//   - Swapped-operand MFMA D[gate_col][act_row]; coalesced epilogue LDS
//     writes (1 b128 + 1 b64); h recurrence in f32 regs; bf16 on MFMA paths.

#define T_STEPS 64
#define HID 128
#define NL 3
#define RB 16
#define NTHR 512
#define NBLK 256
#define LSTR 136   // bf16 row stride (shorts): 272 B, 16B-aligned
#define ASTR 132   // f32 act row stride
#define TC 8       // timesteps per x-chunk
#define NC 8       // chunks per layer

typedef __attribute__((ext_vector_type(8))) short bf16x8;
typedef __attribute__((ext_vector_type(4))) short short4v;
typedef __attribute__((ext_vector_type(4))) float f32x4;

static __device__ __forceinline__ short f2bf_s(float f) {
  __hip_bfloat16 b = __float2bfloat16(f);
  return __builtin_bit_cast(short, b);
}
__device__ __forceinline__ float sigm(float v) { return 1.f / (1.f + __expf(-v)); }
__device__ __forceinline__ float tanh_f(float v) { return 1.f - 2.f / (__expf(2.f * v) + 1.f); }

__global__ __launch_bounds__(NTHR, 1) void gru7(
    const float* __restrict__ x, const int* __restrict__ invalid,
    const float* __restrict__ w_ih, const float* __restrict__ w_hh,
    const float* __restrict__ b_ih, const float* __restrict__ b_hh,
    float* out)
{
  __shared__ short s_x[2][TC * RB * LSTR];  // 2 x 34.8 KB x-chunks (bf16)
  __shared__ short s_h[2][RB * LSTR];       // h bf16 (masked), dbuf
  __shared__ float s_act[2][RB * ASTR];     // f32 activation out-staging, dbuf
  __shared__ int   s_msk[T_STEPS * RB];     // invalid mask, t-major

  const int tid = threadIdx.x;
  const int wave = tid >> 6, lane = tid & 63;
  const int lr = lane & 15, lq = lane >> 4;
  const int row_base = (int)blockIdx.x * RB;
  const int srow = tid >> 5, scol = (tid & 31) * 4;  // coalesced f32x4 map

  for (int i = tid; i < T_STEPS * RB; i += NTHR) {
    const int t = i >> 4, r = i & 15;
    s_msk[i] = invalid[(size_t)(row_base + r) * T_STEPS + t];
  }

  for (int l = 0; l < NL; ++l) {
    // ---- per layer: weights -> bf16 register fragments (A-operand) ----
    bf16x8 wI[3][4], wH[3][4];
#pragma unroll
    for (int g = 0; g < 3; ++g)
#pragma unroll
      for (int kf = 0; kf < 4; ++kf) {
        const int wrow = g * HID + wave * 16 + lr;  // M row (gate col) = lane&15
        const int kofs = kf * 32 + lq * 8;
        const float* pI = w_ih + ((size_t)l * 3 * HID + wrow) * HID + kofs;
        const float* pH = w_hh + ((size_t)l * 3 * HID + wrow) * HID + kofs;
        float4 a = *(const float4*)pI, b = *(const float4*)(pI + 4);
        float vi[8] = {a.x, a.y, a.z, a.w, b.x, b.y, b.z, b.w};
        float4 c = *(const float4*)pH, d = *(const float4*)(pH + 4);
        float vh[8] = {c.x, c.y, c.z, c.w, d.x, d.y, d.z, d.w};
#pragma unroll
        for (int j = 0; j < 8; ++j) {
          wI[g][kf][j] = f2bf_s(vi[j]);
          wH[g][kf][j] = f2bf_s(vh[j]);
        }
      }
    float bRZ0[4], bRZ1[4], bNi[4], bNh[4];  // gate col = wave*16+lq*4+ri
#pragma unroll
    for (int ri = 0; ri < 4; ++ri) {
      const int c = wave * 16 + lq * 4 + ri;
      const size_t base = (size_t)l * 3 * HID;
      bRZ0[ri] = b_ih[base + c] + b_hh[base + c];
      bRZ1[ri] = b_ih[base + HID + c] + b_hh[base + HID + c];
      bNi[ri]  = b_ih[base + 2 * HID + c];
      bNh[ri]  = b_hh[base + 2 * HID + c];
    }

    const float* src = (l == 0) ? x : (const float*)out;
    // ---- h := 0; stage chunk 0 ----
    for (int i = tid; i < RB * LSTR; i += NTHR) s_h[0][i] = 0;
#pragma unroll
    for (int j = 0; j < TC; ++j) {
      float4 v = *(const float4*)(src + ((size_t)(row_base + srow) * T_STEPS + j) * HID + scol);
      short4v c4 = {f2bf_s(v.x), f2bf_s(v.y), f2bf_s(v.z), f2bf_s(v.w)};
      *(short4v*)&s_x[0][(j * RB + srow) * LSTR + scol] = c4;
    }
    __syncthreads();

    // ---- prologue: gI(0) ----
    f32x4 gA0 = {bRZ0[0], bRZ0[1], bRZ0[2], bRZ0[3]};
    f32x4 gA1 = {bRZ1[0], bRZ1[1], bRZ1[2], bRZ1[3]};
    f32x4 gAn = {bNi[0], bNi[1], bNi[2], bNi[3]};
#pragma unroll
    for (int kf = 0; kf < 4; ++kf) {
      bf16x8 xh = *(const bf16x8*)&s_x[0][lr * LSTR + kf * 32 + lq * 8];
      gA0 = __builtin_amdgcn_mfma_f32_16x16x32_bf16(wI[0][kf], xh, gA0, 0, 0, 0);
      gA1 = __builtin_amdgcn_mfma_f32_16x16x32_bf16(wI[1][kf], xh, gA1, 0, 0, 0);
      gAn = __builtin_amdgcn_mfma_f32_16x16x32_bf16(wI[2][kf], xh, gAn, 0, 0, 0);
    }
    float hprev[4] = {0.f, 0.f, 0.f, 0.f};

    for (int c = 0; c < NC; ++c) {
      const int buf = c & 1;
      float4 pin[TC];
      // ---- A: issue next chunk's global loads (converted at cj==2) ----
      if (c < NC - 1) {
#pragma unroll
        for (int j = 0; j < TC; ++j)
          pin[j] = *(const float4*)(src + ((size_t)(row_base + srow) * T_STEPS +
                                          ((c + 1) * TC + j)) * HID + scol);
      }
#pragma unroll
      for (int cj = 0; cj < TC; ++cj) {
        const int t = c * TC + cj;
        const int p = cj & 1;
        // ---- B: deferred out-store of act(t-1) (stays in flight) ----
        if (t > 0) {
          float4 a = *(const float4*)&s_act[p][srow * ASTR + scol];
          *(float4*)(out + ((size_t)(row_base + srow) * T_STEPS + (t - 1)) * HID + scol) = a;
        }
        const int mk = s_msk[t * RB + lr];

        // ---- C: h-side MFMAs (the only barrier-dependent ones) ----
        f32x4 aH0 = (f32x4)(0.f), aH1 = (f32x4)(0.f);
        f32x4 aHn = {bNh[0], bNh[1], bNh[2], bNh[3]};
#pragma unroll
        for (int kf = 0; kf < 4; ++kf) {
          bf16x8 hh = *(const bf16x8*)&s_h[p][lr * LSTR + kf * 32 + lq * 8];
          aH0 = __builtin_amdgcn_mfma_f32_16x16x32_bf16(wH[0][kf], hh, aH0, 0, 0, 0);
          aH1 = __builtin_amdgcn_mfma_f32_16x16x32_bf16(wH[1][kf], hh, aH1, 0, 0, 0);
          aHn = __builtin_amdgcn_mfma_f32_16x16x32_bf16(wH[2][kf], hh, aHn, 0, 0, 0);
        }

        // ---- D: epilogue (uses gA* from prev cell) ----
        float4 actv;
        short4v hb;
#pragma unroll
        for (int ri = 0; ri < 4; ++ri) {
          float rr = sigm(gA0[ri] + aH0[ri]);
          float zz = sigm(gA1[ri] + aH1[ri]);
          float nn = tanh_f(gAn[ri] + rr * aHn[ri]);
          float hn = nn + zz * (hprev[ri] - nn);
          float hm = mk ? 0.f : hn;
          hprev[ri] = hm;
          ((float*)&actv)[ri] = (l == NL - 1) ? hm : hn;
          hb[ri] = f2bf_s(hm);
        }
        {
          const int cb = wave * 16 + lq * 4;
          *(float4*)&s_act[p ^ 1][lr * ASTR + cb] = actv;
          *(short4v*)&s_h[p ^ 1][lr * LSTR + cb] = hb;
        }

        // ---- E: x-side MFMAs for t+1 (independent of D; overlaps it) ----
        if (!(c == NC - 1 && cj == TC - 1)) {
          f32x4 nI0 = {bRZ0[0], bRZ0[1], bRZ0[2], bRZ0[3]};
          f32x4 nI1 = {bRZ1[0], bRZ1[1], bRZ1[2], bRZ1[3]};
          f32x4 nIn = {bNi[0], bNi[1], bNi[2], bNi[3]};
          const short* xb = (cj < TC - 1)
                                ? &s_x[buf][((cj + 1) * RB + lr) * LSTR + lq * 8]
                                : &s_x[buf ^ 1][lr * LSTR + lq * 8];
#pragma unroll
          for (int kf = 0; kf < 4; ++kf) {
            bf16x8 xh = *(const bf16x8*)(xb + kf * 32);
            nI0 = __builtin_amdgcn_mfma_f32_16x16x32_bf16(wI[0][kf], xh, nI0, 0, 0, 0);
            nI1 = __builtin_amdgcn_mfma_f32_16x16x32_bf16(wI[1][kf], xh, nI1, 0, 0, 0);
            nIn = __builtin_amdgcn_mfma_f32_16x16x32_bf16(wI[2][kf], xh, nIn, 0, 0, 0);
          }
          gA0 = nI0; gA1 = nI1; gAn = nIn;
        }

        // ---- F: convert+write next chunk (2 cells after issue) ----
        if (cj == 2 && c < NC - 1) {
#pragma unroll
          for (int j = 0; j < TC; ++j) {
            short4v c4 = {f2bf_s(pin[j].x), f2bf_s(pin[j].y),
                          f2bf_s(pin[j].z), f2bf_s(pin[j].w)};
            *(short4v*)&s_x[buf ^ 1][(j * RB + srow) * LSTR + scol] = c4;
          }
        }

        // ---- G: LDS-only sync; globals stay in flight ----
        asm volatile("s_waitcnt lgkmcnt(0)" ::: "memory");
        __builtin_amdgcn_s_barrier();
      }
    }
    // ---- flush t=63 activations (in s_act[0]) ----
    {
      float4 a = *(const float4*)&s_act[0][srow * ASTR + scol];
      *(float4*)(out + ((size_t)(row_base + srow) * T_STEPS + (T_STEPS - 1)) * HID + scol) = a;
    }
    __syncthreads();  // full drain: out visible before next layer stages from it
  }
}

extern "C" void kernel_launch(void* const* d_in, const int* in_sizes, int n_in,
                              void* d_out, int out_size, void* d_ws, size_t ws_size,
                              hipStream_t stream) {
  const float* x       = (const float*)d_in[0];
  const int*   invalid = (const int*)d_in[1];
  const float* w_ih    = (const float*)d_in[2];
  const float* w_hh    = (const float*)d_in[3];
  const float* b_ih    = (const float*)d_in[4];
  const float* b_hh    = (const float*)d_in[5];
  gru7<<<dim3(NBLK), dim3(NTHR), 0, stream>>>(x, invalid, w_ih, w_hh, b_ih, b_hh,
                                              (float*)d_out);
}

// Round 8
// 314.508 us; speedup vs baseline: 1.0718x; 1.0718x over previous
//
#include <hip/hip_runtime.h>
#include <hip/hip_bf16.h>

// MultiAgentGRULoop round 8: producer/consumer wave specialization.
//   - 256 blocks x 1024 thr (16 waves -> 4/SIMD, 2x occupancy vs R6).
//   - Waves 0-7 (CONSUMERS): h-side MFMA + GRU epilogue + h write. Hold Wh
//     (full k) in regs. Waves 8-15 (PRODUCERS): x-side MFMA one step ahead,
//     gi(t+1) -> LDS ring; x staged bf16 two steps ahead. Hold Wi in regs.
//   - ONE shared w[3][4] register array per thread (Wi or Wh per path) ->
//     48 weight regs, total ~115 < 128 cap at 16 waves (R5/R7 spill lesson).
//   - gi ring: f32, XOR-swizzled (colblk ^= lr&7, same involution write/read)
//     to spread stride-512B rows across bank groups.
//   - One lgkmcnt+s_barrier per cell; globals stay in flight (R6 technique).
//   - Arithmetic identical to R6: swapped-operand MFMA D[gate_col][act_row],
//     f32 register h recurrence, bf16 MFMA paths, biases folded into C-init.

#define T_STEPS 64
#define HID 128
#define NL 3
#define RB 16
#define NTHR 1024
#define NBLK 256
#define LSTR 136   // bf16 row stride (shorts)
#define ASTR 132   // f32 act row stride

typedef __attribute__((ext_vector_type(8))) short bf16x8;
typedef __attribute__((ext_vector_type(4))) short short4v;
typedef __attribute__((ext_vector_type(4))) float f32x4;

static __device__ __forceinline__ short f2bf_s(float f) {
  __hip_bfloat16 b = __float2bfloat16(f);
  return __builtin_bit_cast(short, b);
}
__device__ __forceinline__ float sigm(float v) { return 1.f / (1.f + __expf(-v)); }
__device__ __forceinline__ float tanh_f(float v) { return 1.f - 2.f / (__expf(2.f * v) + 1.f); }

#define MFMA(A, B, C) __builtin_amdgcn_mfma_f32_16x16x32_bf16((A), (B), (C), 0, 0, 0)

__global__ __launch_bounds__(NTHR, 1) void gru8(
    const float* __restrict__ x, const int* __restrict__ invalid,
    const float* __restrict__ w_ih, const float* __restrict__ w_hh,
    const float* __restrict__ b_ih, const float* __restrict__ b_hh,
    float* out)
{
  __shared__ short s_x[2][RB * LSTR];      // x bf16, 2-slot ring (t parity)
  __shared__ short s_h[2][RB * LSTR];      // h bf16 (masked), dbuf
  __shared__ float s_gi[2][3 * RB * HID];  // gi ring f32, XOR-swizzled cols
  __shared__ float s_act[2][RB * ASTR];    // f32 out-staging, dbuf
  __shared__ int   s_msk[T_STEPS * RB];    // mask, t-major

  const int tid = threadIdx.x;
  const int wave = tid >> 6, lane = tid & 63;
  const int lr = lane & 15, lq = lane >> 4;
  const int row_base = (int)blockIdx.x * RB;
  const bool prod = wave >= 8;
  const int slice = prod ? (wave - 8) : wave;     // 16-col gate slice, 0..7
  const int psr = (tid & 511) >> 5;               // staging row map (per half)
  const int pscol = (tid & 31) * 4;               // staging col (f32x4)
  const int gixor = (((slice * 4 + lq) ^ (lr & 7)) << 2);  // swizzled gi col (f32)
  const int cbcol = slice * 16 + lq * 4;          // epilogue col base

  for (int i = tid; i < T_STEPS * RB; i += NTHR) {
    const int t = i >> 4, r = i & 15;
    s_msk[i] = invalid[(size_t)(row_base + r) * T_STEPS + t];
  }

  for (int l = 0; l < NL; ++l) {
    // ---- weights: producers load Wi, consumers Wh — SAME register array ----
    const float* Wsrc = (prod ? w_ih : w_hh) + (size_t)l * 3 * HID * HID;
    bf16x8 w[3][4];
#pragma unroll
    for (int g = 0; g < 3; ++g)
#pragma unroll
      for (int kf = 0; kf < 4; ++kf) {
        const float* pw = Wsrc + (size_t)(g * HID + slice * 16 + lr) * HID + kf * 32 + lq * 8;
        float4 a = *(const float4*)pw, b = *(const float4*)(pw + 4);
        float vv[8] = {a.x, a.y, a.z, a.w, b.x, b.y, b.z, b.w};
#pragma unroll
        for (int j = 0; j < 8; ++j) w[g][kf][j] = f2bf_s(vv[j]);
      }
    // C-init biases: producer {bi_r+bh_r, bi_z+bh_z, bi_n}; consumer {0,0,bh_n}
    f32x4 binit[3];
#pragma unroll
    for (int ri = 0; ri < 4; ++ri) {
      const int c = slice * 16 + lq * 4 + ri;
      const size_t bb = (size_t)l * 3 * HID;
      if (prod) {
        binit[0][ri] = b_ih[bb + c] + b_hh[bb + c];
        binit[1][ri] = b_ih[bb + HID + c] + b_hh[bb + HID + c];
        binit[2][ri] = b_ih[bb + 2 * HID + c];
      } else {
        binit[0][ri] = 0.f;
        binit[1][ri] = 0.f;
        binit[2][ri] = b_hh[bb + 2 * HID + c];
      }
    }

    const float* src = (l == 0) ? x : (const float*)out;

    // ---- h := 0; producers stage x(0)->s_x[0], x(1)->s_x[1] ----
    for (int i = tid; i < RB * LSTR; i += NTHR) s_h[0][i] = 0;
    if (prod) {
#pragma unroll
      for (int s = 0; s < 2; ++s) {
        float4 v = *(const float4*)(src + ((size_t)(row_base + psr) * T_STEPS + s) * HID + pscol);
        short4v c4 = {f2bf_s(v.x), f2bf_s(v.y), f2bf_s(v.z), f2bf_s(v.w)};
        *(short4v*)&s_x[s][psr * LSTR + pscol] = c4;
      }
    }
    __syncthreads();
    // ---- prologue: gi(0) -> s_gi[0] ----
    if (prod) {
      f32x4 a0 = binit[0], a1 = binit[1], a2 = binit[2];
#pragma unroll
      for (int kf = 0; kf < 4; ++kf) {
        bf16x8 xh = *(const bf16x8*)&s_x[0][lr * LSTR + kf * 32 + lq * 8];
        a0 = MFMA(w[0][kf], xh, a0);
        a1 = MFMA(w[1][kf], xh, a1);
        a2 = MFMA(w[2][kf], xh, a2);
      }
      *(f32x4*)&s_gi[0][(0 * RB + lr) * HID + gixor] = a0;
      *(f32x4*)&s_gi[0][(1 * RB + lr) * HID + gixor] = a1;
      *(f32x4*)&s_gi[0][(2 * RB + lr) * HID + gixor] = a2;
    }
    __syncthreads();

    float hprev[4] = {0.f, 0.f, 0.f, 0.f};

    for (int t = 0; t < T_STEPS; ++t) {
      const int p = t & 1;
      if (!prod) {
        // ---- CONSUMER: out-store(t-1), gi read, h-MFMA, epilogue ----
        if (t > 0) {
          float4 a = *(const float4*)&s_act[p][psr * ASTR + pscol];
          *(float4*)(out + ((size_t)(row_base + psr) * T_STEPS + (t - 1)) * HID + pscol) = a;
        }
        const int mk = s_msk[t * RB + lr];
        f32x4 g0 = *(const f32x4*)&s_gi[p][(0 * RB + lr) * HID + gixor];
        f32x4 g1 = *(const f32x4*)&s_gi[p][(1 * RB + lr) * HID + gixor];
        f32x4 g2 = *(const f32x4*)&s_gi[p][(2 * RB + lr) * HID + gixor];
        f32x4 a0 = (f32x4)(0.f), a1 = (f32x4)(0.f), a2 = binit[2];
#pragma unroll
        for (int kf = 0; kf < 4; ++kf) {
          bf16x8 hh = *(const bf16x8*)&s_h[p][lr * LSTR + kf * 32 + lq * 8];
          a0 = MFMA(w[0][kf], hh, a0);
          a1 = MFMA(w[1][kf], hh, a1);
          a2 = MFMA(w[2][kf], hh, a2);
        }
        float4 actv;
        short4v hb;
#pragma unroll
        for (int ri = 0; ri < 4; ++ri) {
          float rr = sigm(g0[ri] + a0[ri]);
          float zz = sigm(g1[ri] + a1[ri]);
          float nn = tanh_f(g2[ri] + rr * a2[ri]);
          float hn = nn + zz * (hprev[ri] - nn);
          float hm = mk ? 0.f : hn;
          hprev[ri] = hm;
          ((float*)&actv)[ri] = (l == NL - 1) ? hm : hn;  // y masked; inter-layer unmasked
          hb[ri] = f2bf_s(hm);
        }
        *(float4*)&s_act[p ^ 1][lr * ASTR + cbcol] = actv;
        *(short4v*)&s_h[p ^ 1][lr * LSTR + cbcol] = hb;
      } else {
        // ---- PRODUCER: load x(t+2), gi(t+1) MFMA, stage x(t+2) ----
        float4 pin;
        if (t + 2 < T_STEPS)
          pin = *(const float4*)(src + ((size_t)(row_base + psr) * T_STEPS + (t + 2)) * HID + pscol);
        if (t + 1 < T_STEPS) {
          f32x4 a0 = binit[0], a1 = binit[1], a2 = binit[2];
#pragma unroll
          for (int kf = 0; kf < 4; ++kf) {
            bf16x8 xh = *(const bf16x8*)&s_x[p ^ 1][lr * LSTR + kf * 32 + lq * 8];
            a0 = MFMA(w[0][kf], xh, a0);
            a1 = MFMA(w[1][kf], xh, a1);
            a2 = MFMA(w[2][kf], xh, a2);
          }
          *(f32x4*)&s_gi[p ^ 1][(0 * RB + lr) * HID + gixor] = a0;
          *(f32x4*)&s_gi[p ^ 1][(1 * RB + lr) * HID + gixor] = a1;
          *(f32x4*)&s_gi[p ^ 1][(2 * RB + lr) * HID + gixor] = a2;
        }
        if (t + 2 < T_STEPS) {
          short4v c4 = {f2bf_s(pin.x), f2bf_s(pin.y), f2bf_s(pin.z), f2bf_s(pin.w)};
          *(short4v*)&s_x[p][psr * LSTR + pscol] = c4;
        }
      }
      // ---- one LDS-only barrier per cell; globals stay in flight ----
      asm volatile("s_waitcnt lgkmcnt(0)" ::: "memory");
      __builtin_amdgcn_s_barrier();
    }
    // ---- flush t=63 activations (in s_act[0]) ----
    if (!prod) {
      float4 a = *(const float4*)&s_act[0][psr * ASTR + pscol];
      *(float4*)(out + ((size_t)(row_base + psr) * T_STEPS + (T_STEPS - 1)) * HID + pscol) = a;
    }
    __syncthreads();  // full drain: out visible before next layer's producers read it
  }
}

extern "C" void kernel_launch(void* const* d_in, const int* in_sizes, int n_in,
                              void* d_out, int out_size, void* d_ws, size_t ws_size,
                              hipStream_t stream) {
  const float* x       = (const float*)d_in[0];
  const int*   invalid = (const int*)d_in[1];
  const float* w_ih    = (const float*)d_in[2];
  const float* w_hh    = (const float*)d_in[3];
  const float* b_ih    = (const float*)d_in[4];
  const float* b_hh    = (const float*)d_in[5];
  gru8<<<dim3(NBLK), dim3(NTHR), 0, stream>>>(x, invalid, w_ih, w_hh, b_ih, b_hh,
                                              (float*)d_out);
}

// Round 9
// 304.123 us; speedup vs baseline: 1.1084x; 1.0341x over previous
//
#include <hip/hip_runtime.h>
#include <hip/hip_bf16.h>

// MultiAgentGRULoop round 9: 4+4 producer/consumer waves, full register budget.
//   - 256 blocks x 512 thr (8 waves, 1 block/CU, bounds(512,1) -> 256-reg cap;
//     R5/R7/R8 all spilled whenever waves/CU > 8. This keeps R6's envelope).
//   - Waves 0-3 CONSUMERS: gate-slice s = cols s*32..s*32+31 of ALL 3 gates
//     (r,z,n of an h-col in one wave). 24 h-MFMAs + epilogue + h/act writes.
//     Hold the Wh slice (96 regs) all layer.
//   - Waves 4-7 PRODUCERS: same slice of Wi; gi(t+1) = x Wi^T + biases -> LDS
//     ring one step ahead; ALL global traffic (x prefetch t+3, bf16 staging,
//     out-stores) -> recurrence path carries no global ops. Hold Wi slice.
//   - 1 consumer + 1 producer wave per SIMD: epilogue VALU/trans overlaps
//     producer MFMA issue every cell.
//   - One lgkmcnt+s_barrier per cell; globals stay in flight (R6 technique).
//   - gi ring f32 stride 20 (2-way banks); arithmetic identical to R6.

#define T_STEPS 64
#define HID 128
#define NL 3
#define RB 16
#define NTHR 512
#define NBLK 256
#define LSTR 136   // bf16 row stride (shorts)
#define ASTR 132   // f32 act row stride
#define GSTR 20    // f32 gi row stride (2-way bank pattern)

typedef __attribute__((ext_vector_type(8))) short bf16x8;
typedef __attribute__((ext_vector_type(4))) short short4v;
typedef __attribute__((ext_vector_type(4))) float f32x4;

static __device__ __forceinline__ short f2bf_s(float f) {
  __hip_bfloat16 b = __float2bfloat16(f);
  return __builtin_bit_cast(short, b);
}
__device__ __forceinline__ float sigm(float v) { return 1.f / (1.f + __expf(-v)); }
__device__ __forceinline__ float tanh_f(float v) { return 1.f - 2.f / (__expf(2.f * v) + 1.f); }

#define MFMA(A, B, C) __builtin_amdgcn_mfma_f32_16x16x32_bf16((A), (B), (C), 0, 0, 0)

__global__ __launch_bounds__(NTHR, 1) void gru9(
    const float* __restrict__ x, const int* __restrict__ invalid,
    const float* __restrict__ w_ih, const float* __restrict__ w_hh,
    const float* __restrict__ b_ih, const float* __restrict__ b_hh,
    float* out)
{
  __shared__ short s_x[2][RB * LSTR];          // x bf16 ring (slot = t&1)
  __shared__ short s_h[2][RB * LSTR];          // h bf16 (masked), dbuf
  __shared__ float s_gi[2][24 * 16 * GSTR];    // gi ring: 4 slices x 6 tiles x 16 rows
  __shared__ float s_act[2][RB * ASTR];        // f32 out-staging, dbuf
  __shared__ int   s_msk[T_STEPS * RB];        // mask, t-major

  const int tid = threadIdx.x;
  const int wave = tid >> 6, lane = tid & 63;
  const int lr = lane & 15, lq = lane >> 4;
  const bool cons = wave < 4;
  const int s = wave & 3;                       // gate slice 0..3 (cols s*32..+31)
  const int ptid = tid & 255;                   // index within producer/consumer half
  const int psr = ptid >> 5, pscol = (ptid & 31) * 4;  // staging map (rows psr, psr+8)
  const int row_base = (int)blockIdx.x * RB;

  for (int i = tid; i < T_STEPS * RB; i += NTHR) {
    const int t = i >> 4, r = i & 15;
    s_msk[i] = invalid[(size_t)(row_base + r) * T_STEPS + t];
  }

  for (int l = 0; l < NL; ++l) {
    // ---- weights: consumers Wh-slice, producers Wi-slice (same reg array) ----
    const float* Wsrc = (cons ? w_hh : w_ih) + (size_t)l * 3 * HID * HID;
    bf16x8 w[6][4];  // j = gate*2 + u  (u = 16-col half of the 32-col slice)
#pragma unroll
    for (int j = 0; j < 6; ++j)
#pragma unroll
      for (int kf = 0; kf < 4; ++kf) {
        const int wrow = (j >> 1) * HID + s * 32 + (j & 1) * 16 + lr;
        const float* pw = Wsrc + (size_t)wrow * HID + kf * 32 + lq * 8;
        float4 a = *(const float4*)pw, b = *(const float4*)(pw + 4);
        float vv[8] = {a.x, a.y, a.z, a.w, b.x, b.y, b.z, b.w};
#pragma unroll
        for (int e = 0; e < 8; ++e) w[j][kf][e] = f2bf_s(vv[e]);
      }
    // C-init: producer {r,z: bi+bh; n: bi}; consumer {r,z: 0; n: bh}
    f32x4 bC[6];
#pragma unroll
    for (int j = 0; j < 6; ++j)
#pragma unroll
      for (int ri = 0; ri < 4; ++ri) {
        const int g = j >> 1;
        const int c = s * 32 + (j & 1) * 16 + lq * 4 + ri;
        const size_t bb = (size_t)l * 3 * HID + g * HID + c;
        bC[j][ri] = cons ? (g == 2 ? b_hh[bb] : 0.f)
                         : (g < 2 ? b_ih[bb] + b_hh[bb] : b_ih[bb]);
      }

    const float* src = (l == 0) ? x : (const float*)out;

    // ---- prologue: producers stage x(0)->s_x[0], x(1)->s_x[1]; consumers h:=0 ----
    if (!cons) {
#pragma unroll
      for (int st = 0; st < 2; ++st) {
        float4 v0 = *(const float4*)(src + ((size_t)(row_base + psr) * T_STEPS + st) * HID + pscol);
        float4 v1 = *(const float4*)(src + ((size_t)(row_base + psr + 8) * T_STEPS + st) * HID + pscol);
        short4v c0 = {f2bf_s(v0.x), f2bf_s(v0.y), f2bf_s(v0.z), f2bf_s(v0.w)};
        short4v c1 = {f2bf_s(v1.x), f2bf_s(v1.y), f2bf_s(v1.z), f2bf_s(v1.w)};
        *(short4v*)&s_x[st][psr * LSTR + pscol] = c0;
        *(short4v*)&s_x[st][(psr + 8) * LSTR + pscol] = c1;
      }
    } else {
      for (int i = ptid; i < (RB * LSTR) / 4; i += 256)
        *(short4v*)&s_h[0][i * 4] = (short4v){0, 0, 0, 0};
    }
    __syncthreads();

    float4 pin0, pin1;
    if (!cons) {
      // gi(0) -> s_gi[0]
      f32x4 a[6];
#pragma unroll
      for (int j = 0; j < 6; ++j) a[j] = bC[j];
#pragma unroll
      for (int kf = 0; kf < 4; ++kf) {
        bf16x8 xh = *(const bf16x8*)&s_x[0][lr * LSTR + kf * 32 + lq * 8];
#pragma unroll
        for (int j = 0; j < 6; ++j) a[j] = MFMA(w[j][kf], xh, a[j]);
      }
#pragma unroll
      for (int j = 0; j < 6; ++j)
        *(f32x4*)&s_gi[0][((s * 6 + j) * 16 + lr) * GSTR + lq * 4] = a[j];
      // pin := x(2)
      pin0 = *(const float4*)(src + ((size_t)(row_base + psr) * T_STEPS + 2) * HID + pscol);
      pin1 = *(const float4*)(src + ((size_t)(row_base + psr + 8) * T_STEPS + 2) * HID + pscol);
    }
    float hp[2][4] = {{0.f, 0.f, 0.f, 0.f}, {0.f, 0.f, 0.f, 0.f}};
    __syncthreads();

#pragma unroll 2
    for (int t = 0; t < T_STEPS; ++t) {
      const int p = t & 1;
      if (cons) {
        // ---- CONSUMER: gi+h reads, 24 MFMA, epilogue, h/act writes ----
        const int mk = s_msk[t * RB + lr];
        f32x4 g[6], a[6];
#pragma unroll
        for (int j = 0; j < 6; ++j) {
          g[j] = *(const f32x4*)&s_gi[p][((s * 6 + j) * 16 + lr) * GSTR + lq * 4];
          a[j] = bC[j];  // 0 for r,z; bh_n for n tiles
        }
#pragma unroll
        for (int kf = 0; kf < 4; ++kf) {
          bf16x8 hh = *(const bf16x8*)&s_h[p][lr * LSTR + kf * 32 + lq * 8];
#pragma unroll
          for (int j = 0; j < 6; ++j) a[j] = MFMA(w[j][kf], hh, a[j]);
        }
#pragma unroll
        for (int u = 0; u < 2; ++u) {
          float4 actv;
          short4v hb;
#pragma unroll
          for (int ri = 0; ri < 4; ++ri) {
            float rr = sigm(g[u][ri] + a[u][ri]);
            float zz = sigm(g[2 + u][ri] + a[2 + u][ri]);
            float nn = tanh_f(g[4 + u][ri] + rr * a[4 + u][ri]);
            float hn = nn + zz * (hp[u][ri] - nn);
            float hm = mk ? 0.f : hn;
            hp[u][ri] = hm;
            ((float*)&actv)[ri] = (l == NL - 1) ? hm : hn;  // y masked; inter-layer unmasked
            hb[ri] = f2bf_s(hm);
          }
          const int cb = s * 32 + u * 16 + lq * 4;
          *(float4*)&s_act[p ^ 1][lr * ASTR + cb] = actv;
          *(short4v*)&s_h[p ^ 1][lr * LSTR + cb] = hb;
        }
      } else {
        // ---- PRODUCER: out-store(t-1), stage x(t+2), gi(t+1), load x(t+3) ----
        if (t > 0) {
          float4 a0 = *(const float4*)&s_act[p][psr * ASTR + pscol];
          float4 a1 = *(const float4*)&s_act[p][(psr + 8) * ASTR + pscol];
          *(float4*)(out + ((size_t)(row_base + psr) * T_STEPS + (t - 1)) * HID + pscol) = a0;
          *(float4*)(out + ((size_t)(row_base + psr + 8) * T_STEPS + (t - 1)) * HID + pscol) = a1;
        }
        if (t < T_STEPS - 2) {  // pin holds x(t+2) -> s_x[p]
          short4v c0 = {f2bf_s(pin0.x), f2bf_s(pin0.y), f2bf_s(pin0.z), f2bf_s(pin0.w)};
          short4v c1 = {f2bf_s(pin1.x), f2bf_s(pin1.y), f2bf_s(pin1.z), f2bf_s(pin1.w)};
          *(short4v*)&s_x[p][psr * LSTR + pscol] = c0;
          *(short4v*)&s_x[p][(psr + 8) * LSTR + pscol] = c1;
        }
        if (t < T_STEPS - 1) {  // gi(t+1) from s_x[p^1] -> s_gi[p^1]
          f32x4 a[6];
#pragma unroll
          for (int j = 0; j < 6; ++j) a[j] = bC[j];
#pragma unroll
          for (int kf = 0; kf < 4; ++kf) {
            bf16x8 xh = *(const bf16x8*)&s_x[p ^ 1][lr * LSTR + kf * 32 + lq * 8];
#pragma unroll
            for (int j = 0; j < 6; ++j) a[j] = MFMA(w[j][kf], xh, a[j]);
          }
#pragma unroll
          for (int j = 0; j < 6; ++j)
            *(f32x4*)&s_gi[p ^ 1][((s * 6 + j) * 16 + lr) * GSTR + lq * 4] = a[j];
        }
        if (t < T_STEPS - 3) {  // pin := x(t+3)
          pin0 = *(const float4*)(src + ((size_t)(row_base + psr) * T_STEPS + (t + 3)) * HID + pscol);
          pin1 = *(const float4*)(src + ((size_t)(row_base + psr + 8) * T_STEPS + (t + 3)) * HID + pscol);
        }
      }
      // ---- one LDS-only barrier per cell; globals stay in flight ----
      asm volatile("s_waitcnt lgkmcnt(0)" ::: "memory");
      __builtin_amdgcn_s_barrier();
    }
    // ---- flush act(63) (in s_act[0]) ----
    if (!cons) {
      float4 a0 = *(const float4*)&s_act[0][psr * ASTR + pscol];
      float4 a1 = *(const float4*)&s_act[0][(psr + 8) * ASTR + pscol];
      *(float4*)(out + ((size_t)(row_base + psr) * T_STEPS + (T_STEPS - 1)) * HID + pscol) = a0;
      *(float4*)(out + ((size_t)(row_base + psr + 8) * T_STEPS + (T_STEPS - 1)) * HID + pscol) = a1;
    }
    __syncthreads();  // full drain: out visible before next layer's producers read it
  }
}

extern "C" void kernel_launch(void* const* d_in, const int* in_sizes, int n_in,
                              void* d_out, int out_size, void* d_ws, size_t ws_size,
                              hipStream_t stream) {
  const float* x       = (const float*)d_in[0];
  const int*   invalid = (const int*)d_in[1];
  const float* w_ih    = (const float*)d_in[2];
  const float* w_hh    = (const float*)d_in[3];
  const float* b_ih    = (const float*)d_in[4];
  const float* b_hh    = (const float*)d_in[5];
  gru9<<<dim3(NBLK), dim3(NTHR), 0, stream>>>(x, invalid, w_ih, w_hh, b_ih, b_hh,
                                              (float*)d_out);
}